// Round 9
// baseline (104.452 us; speedup 1.0000x reference)
//
#include <hip/hip_runtime.h>
#include <stdint.h>

#define DM 256
#define NHEADS 8
#define DH 32
#define SEQ 2048
#define NB 4
#define MTOT (NB*SEQ)

// scale * log2(e) : scores computed in exp2 domain
#define QSCALE 0.2550351270433207f

typedef __attribute__((ext_vector_type(8))) __bf16 bf16x8;
typedef __attribute__((ext_vector_type(4))) short s16x4;
typedef __attribute__((ext_vector_type(8))) short s16x8;
typedef __attribute__((ext_vector_type(4))) unsigned int u32x4;
typedef __attribute__((ext_vector_type(4))) float f32x4;
typedef __attribute__((ext_vector_type(16))) float f32x16;

__device__ inline short f2bf(float f){
  uint32_t u = __builtin_bit_cast(uint32_t, f);
  u += 0x7fffu + ((u >> 16) & 1u);
  return (short)(u >> 16);
}

// ---------------------------------------------------------------------------
// prep: fp32 weights -> bf16 (Wq scaled by QSCALE). 4 x 65536 elems, 8/thread.
// ---------------------------------------------------------------------------
__global__ __launch_bounds__(256) void prep(
    const float* __restrict__ Wq, const float* __restrict__ Wk,
    const float* __restrict__ Wv, const float* __restrict__ Wo,
    short* __restrict__ Wqb, short* __restrict__ Wkb,
    short* __restrict__ Wvb, short* __restrict__ Wob)
{
  const int i = (blockIdx.x*256 + threadIdx.x)*8;
  const int seg = i >> 16;
  const int off = i & 65535;
  const float* src = seg==0?Wq: seg==1?Wk: seg==2?Wv:Wo;
  short* dst       = seg==0?Wqb: seg==1?Wkb: seg==2?Wvb:Wob;
  const float sc = (seg==0) ? QSCALE : 1.0f;
  float4 a = *(const float4*)(src + off);
  float4 b = *(const float4*)(src + off + 4);
  s16x8 o;
  o[0]=f2bf(a.x*sc); o[1]=f2bf(a.y*sc); o[2]=f2bf(a.z*sc); o[3]=f2bf(a.w*sc);
  o[4]=f2bf(b.x*sc); o[5]=f2bf(b.y*sc); o[6]=f2bf(b.z*sc); o[7]=f2bf(b.w*sc);
  *(s16x8*)(dst + off) = o;
}

// ---------------------------------------------------------------------------
// QKV projection, bf16 W, n-split=2 (8 n-frags/wave) so X is read only 2x.
// Block = 2 waves x 16 rows. mode: 0->Qh [b,h,l,d]; 1->Kh; 2->Vt [b,h,d,l]
// ---------------------------------------------------------------------------
__global__ __launch_bounds__(128) void qkv_proj(
    const float* __restrict__ Xq, const float* __restrict__ Xk, const float* __restrict__ Xv,
    const short* __restrict__ Wqb, const short* __restrict__ Wkb, const short* __restrict__ Wvb,
    const float* __restrict__ bq, const float* __restrict__ bk, const float* __restrict__ bv,
    short* __restrict__ Qh, short* __restrict__ Kh, short* __restrict__ Vt)
{
  const int mode = blockIdx.z;
  const float* X    = mode==0 ? Xq : (mode==1 ? Xk : Xv);
  const short* Wb   = mode==0 ? Wqb : (mode==1 ? Wkb : Wvb);
  const float* bias = mode==0 ? bq : (mode==1 ? bk : bv);
  short* dst        = mode==0 ? Qh : (mode==1 ? Kh : Vt);
  const float bscale = (mode==0) ? QSCALE : 1.0f;

  const int wid = threadIdx.x >> 6, lane = threadIdx.x & 63;
  const int lr = lane & 15, lg = lane >> 4;
  const int m0 = blockIdx.x*32 + wid*16;
  const int nf0 = blockIdx.y*8;

  f32x4 acc[8] = {};

  #pragma unroll
  for (int kc = 0; kc < 8; ++kc) {
    const int k0 = kc*32 + lg*8;
    const float* ap = X + (size_t)(m0 + lr)*DM + k0;
    float4 a0 = *(const float4*)ap;
    float4 a1 = *(const float4*)(ap + 4);
    bf16x8 a;
    a[0]=(__bf16)a0.x; a[1]=(__bf16)a0.y; a[2]=(__bf16)a0.z; a[3]=(__bf16)a0.w;
    a[4]=(__bf16)a1.x; a[5]=(__bf16)a1.y; a[6]=(__bf16)a1.z; a[7]=(__bf16)a1.w;
    #pragma unroll
    for (int nfi=0; nfi<8; ++nfi) {
      bf16x8 b = *(const bf16x8*)(Wb + (size_t)((nf0+nfi)*16 + lr)*DM + k0);
      acc[nfi] = __builtin_amdgcn_mfma_f32_16x16x32_bf16(a, b, acc[nfi], 0,0,0);
    }
  }

  const int bb  = m0 >> 11;
  const int li0 = (m0 & (SEQ-1)) + lg*4;
  #pragma unroll
  for (int nfi=0; nfi<8; ++nfi) {
    const int col = (nf0+nfi)*16 + lr;
    const float bv_ = bias[col]*bscale;
    const int h = col >> 5, d = col & 31;
    if (mode < 2) {
      #pragma unroll
      for (int r=0;r<4;r++)
        dst[((size_t)(bb*NHEADS + h)*SEQ + (li0 + r))*DH + d] = f2bf(acc[nfi][r] + bv_);
    } else {
      s16x4 pk;
      #pragma unroll
      for (int r=0;r<4;r++) pk[r] = f2bf(acc[nfi][r] + bv_);
      *(s16x4*)(dst + ((size_t)(bb*NHEADS + h)*DH + d)*SEQ + li0) = pk;
    }
  }
}

// ---------------------------------------------------------------------------
// Flash attention, 32x32x16 MFMA, swapped-QK, no max tracking (exp2-domain
// scores bounded). 4-way kv split per block; (l,O) merge is pure addition.
// P^T in-register via cvt_pk + permlane32_swap. Prefetch + sched_barrier.
// XCD locality: grid = (bh, qblock) so linear id = bh + 32*qy; 32 % 8 == 0
// => all q-blocks of a head land on XCD (bh & 7); per-XCD K/V = 4 heads
// = 1 MB, L2-resident (fixes the 3x HBM re-fetch seen in round 8).
// ---------------------------------------------------------------------------
#if __has_builtin(__builtin_amdgcn_permlane32_swap)
typedef unsigned int u32x2v __attribute__((ext_vector_type(2)));
#define PSWAP(a_, b_) do { u32x2v r_ = __builtin_amdgcn_permlane32_swap((a_), (b_), false, false); (a_) = r_[0]; (b_) = r_[1]; } while(0)
#else
#define PSWAP(a_, b_) asm("s_nop 1\n\tv_permlane32_swap_b32 %0, %1" : "+v"(a_), "+v"(b_))
#endif

#define LOADKV(K0_,K1_,V0_,V1_, kvb_) do { \
  const short* kp_ = Kb + (size_t)((kvb_) + l31)*DH + hi8; \
  K0_ = *(const bf16x8*)kp_; K1_ = *(const bf16x8*)(kp_ + 16); \
  const short* vp_ = Vb + (size_t)l31*SEQ + (kvb_) + hi8; \
  V0_ = *(const bf16x8*)vp_; V1_ = *(const bf16x8*)(vp_ + 16); \
} while(0)

#define ATTN_TILE(K0_, K1_, V0_, V1_) do { \
  f32x16 S_ = __builtin_amdgcn_mfma_f32_32x32x16_bf16(K0_, Q0, zf16, 0,0,0); \
  S_ = __builtin_amdgcn_mfma_f32_32x32x16_bf16(K1_, Q1, S_, 0,0,0); \
  float p_[16]; \
  _Pragma("unroll") for (int r_=0;r_<16;r_++) p_[r_] = __builtin_amdgcn_exp2f(S_[r_]); \
  lrun += (((p_[0]+p_[1])+(p_[2]+p_[3]))+((p_[4]+p_[5])+(p_[6]+p_[7]))) \
        + (((p_[8]+p_[9])+(p_[10]+p_[11]))+((p_[12]+p_[13])+(p_[14]+p_[15]))); \
  uint32_t pa_, pb_, pc_, pd_; \
  asm("v_cvt_pk_bf16_f32 %0, %1, %2" : "=v"(pa_) : "v"(p_[0]), "v"(p_[1])); \
  asm("v_cvt_pk_bf16_f32 %0, %1, %2" : "=v"(pb_) : "v"(p_[2]), "v"(p_[3])); \
  asm("v_cvt_pk_bf16_f32 %0, %1, %2" : "=v"(pc_) : "v"(p_[4]), "v"(p_[5])); \
  asm("v_cvt_pk_bf16_f32 %0, %1, %2" : "=v"(pd_) : "v"(p_[6]), "v"(p_[7])); \
  PSWAP(pa_, pc_); PSWAP(pb_, pd_); \
  { u32x4 w_ = {pa_, pb_, pc_, pd_}; \
    O = __builtin_amdgcn_mfma_f32_32x32x16_bf16(V0_, __builtin_bit_cast(bf16x8, w_), O, 0,0,0); } \
  asm("v_cvt_pk_bf16_f32 %0, %1, %2" : "=v"(pa_) : "v"(p_[8]),  "v"(p_[9])); \
  asm("v_cvt_pk_bf16_f32 %0, %1, %2" : "=v"(pb_) : "v"(p_[10]), "v"(p_[11])); \
  asm("v_cvt_pk_bf16_f32 %0, %1, %2" : "=v"(pc_) : "v"(p_[12]), "v"(p_[13])); \
  asm("v_cvt_pk_bf16_f32 %0, %1, %2" : "=v"(pd_) : "v"(p_[14]), "v"(p_[15])); \
  PSWAP(pa_, pc_); PSWAP(pb_, pd_); \
  { u32x4 w_ = {pa_, pb_, pc_, pd_}; \
    O = __builtin_amdgcn_mfma_f32_32x32x16_bf16(V1_, __builtin_bit_cast(bf16x8, w_), O, 0,0,0); } \
} while(0)

__global__ __launch_bounds__(256) void attn(
    const short* __restrict__ Qh, const short* __restrict__ Kh,
    const short* __restrict__ Vt, short* __restrict__ ctx)
{
  __shared__ float Ll[3][64];
  __shared__ float Ol[3][64][17];
  const int wid = threadIdx.x >> 6, lane = threadIdx.x & 63;
  const int l31 = lane & 31, hi8 = (lane >> 5)*8;
  const int bh = blockIdx.x;              // XCD = bh & 7 (32 % 8 == 0)
  const int q0 = blockIdx.y*32;
  const int kv0 = wid * (SEQ/4);

  const short* Kb = Kh + (size_t)bh*SEQ*DH;
  const short* Vb = Vt + (size_t)bh*DH*SEQ;

  // Q B-frags over the two d-chunks: (q = q0+l31, k = d = c*16 + hi*8 + j)
  const short* qp = Qh + ((size_t)bh*SEQ + q0 + l31)*DH + hi8;
  const bf16x8 Q0 = *(const bf16x8*)(qp);
  const bf16x8 Q1 = *(const bf16x8*)(qp + 16);

  f32x16 O = {};
  float lrun = 0.f;
  const f32x16 zf16 = {};

  bf16x8 Ka0,Ka1,Va0,Va1, Kc0,Kc1,Vc0,Vc1;
  LOADKV(Ka0,Ka1,Va0,Va1, kv0);

  #pragma unroll 2
  for (int t = 0; t < 16; t += 2) {      // 16 tiles of 32 kv each (quarter)
    LOADKV(Kc0,Kc1,Vc0,Vc1, kv0 + (t+1)*32);
    __builtin_amdgcn_sched_barrier(0);
    ATTN_TILE(Ka0,Ka1,Va0,Va1);
    LOADKV(Ka0,Ka1,Va0,Va1, kv0 + ((t+2)&15)*32);
    __builtin_amdgcn_sched_barrier(0);
    ATTN_TILE(Kc0,Kc1,Vc0,Vc1);
  }

  lrun += __shfl_xor(lrun, 32);          // both kv-row halves of this wave

  if (wid) {
    Ll[wid-1][lane] = lrun;
    #pragma unroll
    for (int r=0;r<16;r++) Ol[wid-1][lane][r] = O[r];
  }
  __syncthreads();
  if (wid == 0) {
    #pragma unroll
    for (int w=0;w<3;w++){
      lrun += Ll[w][lane];
      #pragma unroll
      for (int r=0;r<16;r++) O[r] += Ol[w][lane][r];
    }
    const float inv = 1.0f / lrun;
    // O^T lane layout: q = l31, d = (reg&3) + 8*(reg>>2) + (hi8>>1)
    const int bb = bh >> 3, hh = bh & 7;
    short* cp = ctx + ((size_t)(bb*SEQ) + q0 + l31)*DM + hh*DH + (hi8 >> 1);
    #pragma unroll
    for (int rg=0; rg<4; ++rg) {
      s16x4 o;
      #pragma unroll
      for (int r=0;r<4;r++) o[r] = f2bf(O[rg*4+r]*inv);
      *(s16x4*)(cp + rg*8) = o;
    }
  }
}

// ---------------------------------------------------------------------------
// out = ctx @ Wo^T + bo; x = out + query; LayerNorm(x).
// Block = 4 waves on ONE 16-row group; wave w covers cols [w*64,+64).
// LN stats combined across waves via tiny LDS exchange. 8 waves/CU.
// ---------------------------------------------------------------------------
__global__ __launch_bounds__(256) void out_ln(
    const short* __restrict__ ctx, const short* __restrict__ Wob,
    const float* __restrict__ bo, const float* __restrict__ resid,
    const float* __restrict__ ln_g, const float* __restrict__ ln_b,
    float* __restrict__ out)
{
  __shared__ float2 red[4][16];
  const int wid = threadIdx.x >> 6, lane = threadIdx.x & 63;
  const int lr = lane & 15, lg = lane >> 4;
  const int m0 = blockIdx.x*16;
  const int c0 = wid*64;

  f32x4 acc[4] = {};
  #pragma unroll
  for (int kc=0; kc<8; ++kc) {
    const int k0 = kc*32 + lg*8;
    bf16x8 a = *(const bf16x8*)(ctx + (size_t)(m0 + lr)*DM + k0);
    #pragma unroll
    for (int nf=0; nf<4; ++nf) {
      bf16x8 b = *(const bf16x8*)(Wob + (size_t)(c0 + nf*16 + lr)*DM + k0);
      acc[nf] = __builtin_amdgcn_mfma_f32_16x16x32_bf16(a, b, acc[nf], 0,0,0);
    }
  }

  float xv[4][4];
  #pragma unroll
  for (int r=0;r<4;r++) {
    const int m = m0 + lg*4 + r;
    float s = 0.f, s2 = 0.f;
    #pragma unroll
    for (int nf=0; nf<4; ++nf) {
      const int col = c0 + nf*16 + lr;
      float v = acc[nf][r] + bo[col] + resid[(size_t)m*DM + col];
      xv[r][nf] = v; s += v; s2 += v*v;
    }
    #pragma unroll
    for (int off=1; off<16; off<<=1) { s += __shfl_xor(s, off); s2 += __shfl_xor(s2, off); }
    if (lr == 0) red[wid][lg*4+r] = make_float2(s, s2);
  }
  __syncthreads();
  #pragma unroll
  for (int r=0;r<4;r++) {
    const int m = m0 + lg*4 + r;
    float s = 0.f, s2 = 0.f;
    #pragma unroll
    for (int w=0;w<4;w++){ float2 t = red[w][lg*4+r]; s += t.x; s2 += t.y; }
    const float mean = s * (1.0f/DM);
    const float var  = s2 * (1.0f/DM) - mean*mean;
    const float rstd = rsqrtf(var + 1e-5f);
    #pragma unroll
    for (int nf=0; nf<4; ++nf) {
      const int col = c0 + nf*16 + lr;
      out[(size_t)m*DM + col] = (xv[r][nf] - mean)*rstd*ln_g[col] + ln_b[col];
    }
  }
}

extern "C" void kernel_launch(void* const* d_in, const int* in_sizes, int n_in,
                              void* d_out, int out_size, void* d_ws, size_t ws_size,
                              hipStream_t stream) {
  const float* query = (const float*)d_in[0];
  const float* key   = (const float*)d_in[1];
  const float* value = (const float*)d_in[2];
  const float* Wq    = (const float*)d_in[3];
  const float* bq    = (const float*)d_in[4];
  const float* Wk    = (const float*)d_in[5];
  const float* bk    = (const float*)d_in[6];
  const float* Wv    = (const float*)d_in[7];
  const float* bv    = (const float*)d_in[8];
  const float* Wo    = (const float*)d_in[9];
  const float* bo    = (const float*)d_in[10];
  const float* ln_g  = (const float*)d_in[11];
  const float* ln_b  = (const float*)d_in[12];
  float* out = (float*)d_out;

  const size_t HSZ = (size_t)NB*NHEADS*SEQ*DH;   // 2,097,152
  short* Qh  = (short*)d_ws;
  short* Kh  = Qh + HSZ;
  short* Vt  = Kh + HSZ;
  short* ctx = Vt + HSZ;
  short* Wqb = ctx + (size_t)MTOT*DM;
  short* Wkb = Wqb + DM*DM;
  short* Wvb = Wkb + DM*DM;
  short* Wob = Wvb + DM*DM;   // total ws: ~17 MB

  prep<<<dim3(128), 256, 0, stream>>>(Wq, Wk, Wv, Wo, Wqb, Wkb, Wvb, Wob);
  qkv_proj<<<dim3(MTOT/32, 2, 3), 128, 0, stream>>>(
      query, key, value, Wqb, Wkb, Wvb, bq, bk, bv, Qh, Kh, Vt);
  attn<<<dim3(NB*NHEADS, SEQ/32), 256, 0, stream>>>(Qh, Kh, Vt, ctx);
  out_ln<<<dim3(MTOT/16), 256, 0, stream>>>(ctx, Wob, bo, query, ln_g, ln_b, out);
}

// Round 10
// 89.715 us; speedup vs baseline: 1.1643x; 1.1643x over previous
//
#include <hip/hip_runtime.h>
#include <stdint.h>

#define DM 256
#define NHEADS 8
#define DH 32
#define SEQ 2048
#define NB 4
#define MTOT (NB*SEQ)

// scale * log2(e) : scores computed in exp2 domain
#define QSCALE 0.2550351270433207f

typedef __attribute__((ext_vector_type(8))) __bf16 bf16x8;
typedef __attribute__((ext_vector_type(4))) short s16x4;
typedef __attribute__((ext_vector_type(8))) short s16x8;
typedef __attribute__((ext_vector_type(4))) unsigned int u32x4;
typedef __attribute__((ext_vector_type(4))) float f32x4;
typedef __attribute__((ext_vector_type(16))) float f32x16;

__device__ inline short f2bf(float f){
  uint32_t u = __builtin_bit_cast(uint32_t, f);
  u += 0x7fffu + ((u >> 16) & 1u);
  return (short)(u >> 16);
}

// ---------------------------------------------------------------------------
// prep: fp32 weights -> bf16 (Wq scaled by QSCALE). 4 x 65536 elems, 8/thread.
// ---------------------------------------------------------------------------
__global__ __launch_bounds__(256) void prep(
    const float* __restrict__ Wq, const float* __restrict__ Wk,
    const float* __restrict__ Wv, const float* __restrict__ Wo,
    short* __restrict__ Wqb, short* __restrict__ Wkb,
    short* __restrict__ Wvb, short* __restrict__ Wob)
{
  const int i = (blockIdx.x*256 + threadIdx.x)*8;
  const int seg = i >> 16;
  const int off = i & 65535;
  const float* src = seg==0?Wq: seg==1?Wk: seg==2?Wv:Wo;
  short* dst       = seg==0?Wqb: seg==1?Wkb: seg==2?Wvb:Wob;
  const float sc = (seg==0) ? QSCALE : 1.0f;
  float4 a = *(const float4*)(src + off);
  float4 b = *(const float4*)(src + off + 4);
  s16x8 o;
  o[0]=f2bf(a.x*sc); o[1]=f2bf(a.y*sc); o[2]=f2bf(a.z*sc); o[3]=f2bf(a.w*sc);
  o[4]=f2bf(b.x*sc); o[5]=f2bf(b.y*sc); o[6]=f2bf(b.z*sc); o[7]=f2bf(b.w*sc);
  *(s16x8*)(dst + off) = o;
}

// ---------------------------------------------------------------------------
// QKV projection, bf16 W, n-split=2 (8 n-frags/wave) so X is read only 2x.
// mode: 0->Qh [b,h,l,d]; 1->Kh [b,h,l,d];
//       2->Vt TILED: [b,h][kv_tile=64][d=32][kv_in_tile=32] so the PV
//       operand tile (32 kv x 32 d) is one contiguous 2KB block (the old
//       [d][kv] layout made each V load a 32-line gather over 128KB).
// ---------------------------------------------------------------------------
__global__ __launch_bounds__(128) void qkv_proj(
    const float* __restrict__ Xq, const float* __restrict__ Xk, const float* __restrict__ Xv,
    const short* __restrict__ Wqb, const short* __restrict__ Wkb, const short* __restrict__ Wvb,
    const float* __restrict__ bq, const float* __restrict__ bk, const float* __restrict__ bv,
    short* __restrict__ Qh, short* __restrict__ Kh, short* __restrict__ Vt)
{
  const int mode = blockIdx.z;
  const float* X    = mode==0 ? Xq : (mode==1 ? Xk : Xv);
  const short* Wb   = mode==0 ? Wqb : (mode==1 ? Wkb : Wvb);
  const float* bias = mode==0 ? bq : (mode==1 ? bk : bv);
  short* dst        = mode==0 ? Qh : (mode==1 ? Kh : Vt);
  const float bscale = (mode==0) ? QSCALE : 1.0f;

  const int wid = threadIdx.x >> 6, lane = threadIdx.x & 63;
  const int lr = lane & 15, lg = lane >> 4;
  const int m0 = blockIdx.x*32 + wid*16;
  const int nf0 = blockIdx.y*8;

  f32x4 acc[8] = {};

  #pragma unroll
  for (int kc = 0; kc < 8; ++kc) {
    const int k0 = kc*32 + lg*8;
    const float* ap = X + (size_t)(m0 + lr)*DM + k0;
    float4 a0 = *(const float4*)ap;
    float4 a1 = *(const float4*)(ap + 4);
    bf16x8 a;
    a[0]=(__bf16)a0.x; a[1]=(__bf16)a0.y; a[2]=(__bf16)a0.z; a[3]=(__bf16)a0.w;
    a[4]=(__bf16)a1.x; a[5]=(__bf16)a1.y; a[6]=(__bf16)a1.z; a[7]=(__bf16)a1.w;
    #pragma unroll
    for (int nfi=0; nfi<8; ++nfi) {
      bf16x8 b = *(const bf16x8*)(Wb + (size_t)((nf0+nfi)*16 + lr)*DM + k0);
      acc[nfi] = __builtin_amdgcn_mfma_f32_16x16x32_bf16(a, b, acc[nfi], 0,0,0);
    }
  }

  const int bb  = m0 >> 11;
  const int li0 = (m0 & (SEQ-1)) + lg*4;
  #pragma unroll
  for (int nfi=0; nfi<8; ++nfi) {
    const int col = (nf0+nfi)*16 + lr;
    const float bv_ = bias[col]*bscale;
    const int h = col >> 5, d = col & 31;
    if (mode < 2) {
      #pragma unroll
      for (int r=0;r<4;r++)
        dst[((size_t)(bb*NHEADS + h)*SEQ + (li0 + r))*DH + d] = f2bf(acc[nfi][r] + bv_);
    } else {
      s16x4 pk;
      #pragma unroll
      for (int r=0;r<4;r++) pk[r] = f2bf(acc[nfi][r] + bv_);
      // tile t = li0>>5, c = li0&31 (li0%4==0, c<=28 -> no tile straddle)
      *(s16x4*)(dst + (((size_t)(bb*NHEADS + h)*(SEQ/32) + (li0>>5))*DH + d)*32 + (li0&31)) = pk;
    }
  }
}

// ---------------------------------------------------------------------------
// Flash attention, 32x32x16 MFMA, swapped-QK, no max tracking (exp2-domain
// scores bounded). 4-way kv split per block; (l,O) merge is pure addition.
// P^T in-register via cvt_pk + permlane32_swap. Prefetch + sched_barrier.
// XCD locality: grid = (bh, qblock); 32 % 8 == 0 => head -> fixed XCD.
// V in tiled layout: each 32x32 V-tile is contiguous 2KB -> V loads are
// 16-line contiguous (was 32-line/128KB gather).
// ---------------------------------------------------------------------------
#if __has_builtin(__builtin_amdgcn_permlane32_swap)
typedef unsigned int u32x2v __attribute__((ext_vector_type(2)));
#define PSWAP(a_, b_) do { u32x2v r_ = __builtin_amdgcn_permlane32_swap((a_), (b_), false, false); (a_) = r_[0]; (b_) = r_[1]; } while(0)
#else
#define PSWAP(a_, b_) asm("s_nop 1\n\tv_permlane32_swap_b32 %0, %1" : "+v"(a_), "+v"(b_))
#endif

#define LOADKV(K0_,K1_,V0_,V1_, kvb_) do { \
  const short* kp_ = Kb + (size_t)((kvb_) + l31)*DH + hi8; \
  K0_ = *(const bf16x8*)kp_; K1_ = *(const bf16x8*)(kp_ + 16); \
  const short* vp_ = Vb + ((size_t)(((kvb_) >> 5)*32) + l31)*32 + hi8; \
  V0_ = *(const bf16x8*)vp_; V1_ = *(const bf16x8*)(vp_ + 16); \
} while(0)

#define ATTN_TILE(K0_, K1_, V0_, V1_) do { \
  f32x16 S_ = __builtin_amdgcn_mfma_f32_32x32x16_bf16(K0_, Q0, zf16, 0,0,0); \
  S_ = __builtin_amdgcn_mfma_f32_32x32x16_bf16(K1_, Q1, S_, 0,0,0); \
  float p_[16]; \
  _Pragma("unroll") for (int r_=0;r_<16;r_++) p_[r_] = __builtin_amdgcn_exp2f(S_[r_]); \
  lrun += (((p_[0]+p_[1])+(p_[2]+p_[3]))+((p_[4]+p_[5])+(p_[6]+p_[7]))) \
        + (((p_[8]+p_[9])+(p_[10]+p_[11]))+((p_[12]+p_[13])+(p_[14]+p_[15]))); \
  uint32_t pa_, pb_, pc_, pd_; \
  asm("v_cvt_pk_bf16_f32 %0, %1, %2" : "=v"(pa_) : "v"(p_[0]), "v"(p_[1])); \
  asm("v_cvt_pk_bf16_f32 %0, %1, %2" : "=v"(pb_) : "v"(p_[2]), "v"(p_[3])); \
  asm("v_cvt_pk_bf16_f32 %0, %1, %2" : "=v"(pc_) : "v"(p_[4]), "v"(p_[5])); \
  asm("v_cvt_pk_bf16_f32 %0, %1, %2" : "=v"(pd_) : "v"(p_[6]), "v"(p_[7])); \
  PSWAP(pa_, pc_); PSWAP(pb_, pd_); \
  { u32x4 w_ = {pa_, pb_, pc_, pd_}; \
    O = __builtin_amdgcn_mfma_f32_32x32x16_bf16(V0_, __builtin_bit_cast(bf16x8, w_), O, 0,0,0); } \
  asm("v_cvt_pk_bf16_f32 %0, %1, %2" : "=v"(pa_) : "v"(p_[8]),  "v"(p_[9])); \
  asm("v_cvt_pk_bf16_f32 %0, %1, %2" : "=v"(pb_) : "v"(p_[10]), "v"(p_[11])); \
  asm("v_cvt_pk_bf16_f32 %0, %1, %2" : "=v"(pc_) : "v"(p_[12]), "v"(p_[13])); \
  asm("v_cvt_pk_bf16_f32 %0, %1, %2" : "=v"(pd_) : "v"(p_[14]), "v"(p_[15])); \
  PSWAP(pa_, pc_); PSWAP(pb_, pd_); \
  { u32x4 w_ = {pa_, pb_, pc_, pd_}; \
    O = __builtin_amdgcn_mfma_f32_32x32x16_bf16(V1_, __builtin_bit_cast(bf16x8, w_), O, 0,0,0); } \
} while(0)

__global__ __launch_bounds__(256) void attn(
    const short* __restrict__ Qh, const short* __restrict__ Kh,
    const short* __restrict__ Vt, short* __restrict__ ctx)
{
  __shared__ float Ll[3][64];
  __shared__ float Ol[3][64][17];
  const int wid = threadIdx.x >> 6, lane = threadIdx.x & 63;
  const int l31 = lane & 31, hi8 = (lane >> 5)*8;
  const int bh = blockIdx.x;              // XCD = bh & 7 (32 % 8 == 0)
  const int q0 = blockIdx.y*32;
  const int kv0 = wid * (SEQ/4);

  const short* Kb = Kh + (size_t)bh*SEQ*DH;
  const short* Vb = Vt + (size_t)bh*SEQ*DH;   // tiled layout, same total size

  // Q B-frags over the two d-chunks: (q = q0+l31, k = d = c*16 + hi*8 + j)
  const short* qp = Qh + ((size_t)bh*SEQ + q0 + l31)*DH + hi8;
  const bf16x8 Q0 = *(const bf16x8*)(qp);
  const bf16x8 Q1 = *(const bf16x8*)(qp + 16);

  f32x16 O = {};
  float lrun = 0.f;
  const f32x16 zf16 = {};

  bf16x8 Ka0,Ka1,Va0,Va1, Kc0,Kc1,Vc0,Vc1;
  LOADKV(Ka0,Ka1,Va0,Va1, kv0);

  #pragma unroll 2
  for (int t = 0; t < 16; t += 2) {      // 16 tiles of 32 kv each (quarter)
    LOADKV(Kc0,Kc1,Vc0,Vc1, kv0 + (t+1)*32);
    __builtin_amdgcn_sched_barrier(0);
    ATTN_TILE(Ka0,Ka1,Va0,Va1);
    LOADKV(Ka0,Ka1,Va0,Va1, kv0 + ((t+2)&15)*32);
    __builtin_amdgcn_sched_barrier(0);
    ATTN_TILE(Kc0,Kc1,Vc0,Vc1);
  }

  lrun += __shfl_xor(lrun, 32);          // both kv-row halves of this wave

  if (wid) {
    Ll[wid-1][lane] = lrun;
    #pragma unroll
    for (int r=0;r<16;r++) Ol[wid-1][lane][r] = O[r];
  }
  __syncthreads();
  if (wid == 0) {
    #pragma unroll
    for (int w=0;w<3;w++){
      lrun += Ll[w][lane];
      #pragma unroll
      for (int r=0;r<16;r++) O[r] += Ol[w][lane][r];
    }
    const float inv = 1.0f / lrun;
    // O^T lane layout: q = l31, d = (reg&3) + 8*(reg>>2) + (hi8>>1)
    const int bb = bh >> 3, hh = bh & 7;
    short* cp = ctx + ((size_t)(bb*SEQ) + q0 + l31)*DM + hh*DH + (hi8 >> 1);
    #pragma unroll
    for (int rg=0; rg<4; ++rg) {
      s16x4 o;
      #pragma unroll
      for (int r=0;r<4;r++) o[r] = f2bf(O[rg*4+r]*inv);
      *(s16x4*)(cp + rg*8) = o;
    }
  }
}

// ---------------------------------------------------------------------------
// out = ctx @ Wo^T + bo; x = out + query; LayerNorm(x).
// Block = 4 waves on ONE 16-row group; wave w covers cols [w*64,+64).
// LN stats combined across waves via tiny LDS exchange. 8 waves/CU.
// ---------------------------------------------------------------------------
__global__ __launch_bounds__(256) void out_ln(
    const short* __restrict__ ctx, const short* __restrict__ Wob,
    const float* __restrict__ bo, const float* __restrict__ resid,
    const float* __restrict__ ln_g, const float* __restrict__ ln_b,
    float* __restrict__ out)
{
  __shared__ float2 red[4][16];
  const int wid = threadIdx.x >> 6, lane = threadIdx.x & 63;
  const int lr = lane & 15, lg = lane >> 4;
  const int m0 = blockIdx.x*16;
  const int c0 = wid*64;

  f32x4 acc[4] = {};
  #pragma unroll
  for (int kc=0; kc<8; ++kc) {
    const int k0 = kc*32 + lg*8;
    bf16x8 a = *(const bf16x8*)(ctx + (size_t)(m0 + lr)*DM + k0);
    #pragma unroll
    for (int nf=0; nf<4; ++nf) {
      bf16x8 b = *(const bf16x8*)(Wob + (size_t)(c0 + nf*16 + lr)*DM + k0);
      acc[nf] = __builtin_amdgcn_mfma_f32_16x16x32_bf16(a, b, acc[nf], 0,0,0);
    }
  }

  float xv[4][4];
  #pragma unroll
  for (int r=0;r<4;r++) {
    const int m = m0 + lg*4 + r;
    float s = 0.f, s2 = 0.f;
    #pragma unroll
    for (int nf=0; nf<4; ++nf) {
      const int col = c0 + nf*16 + lr;
      float v = acc[nf][r] + bo[col] + resid[(size_t)m*DM + col];
      xv[r][nf] = v; s += v; s2 += v*v;
    }
    #pragma unroll
    for (int off=1; off<16; off<<=1) { s += __shfl_xor(s, off); s2 += __shfl_xor(s2, off); }
    if (lr == 0) red[wid][lg*4+r] = make_float2(s, s2);
  }
  __syncthreads();
  #pragma unroll
  for (int r=0;r<4;r++) {
    const int m = m0 + lg*4 + r;
    float s = 0.f, s2 = 0.f;
    #pragma unroll
    for (int w=0;w<4;w++){ float2 t = red[w][lg*4+r]; s += t.x; s2 += t.y; }
    const float mean = s * (1.0f/DM);
    const float var  = s2 * (1.0f/DM) - mean*mean;
    const float rstd = rsqrtf(var + 1e-5f);
    #pragma unroll
    for (int nf=0; nf<4; ++nf) {
      const int col = c0 + nf*16 + lr;
      out[(size_t)m*DM + col] = (xv[r][nf] - mean)*rstd*ln_g[col] + ln_b[col];
    }
  }
}

extern "C" void kernel_launch(void* const* d_in, const int* in_sizes, int n_in,
                              void* d_out, int out_size, void* d_ws, size_t ws_size,
                              hipStream_t stream) {
  const float* query = (const float*)d_in[0];
  const float* key   = (const float*)d_in[1];
  const float* value = (const float*)d_in[2];
  const float* Wq    = (const float*)d_in[3];
  const float* bq    = (const float*)d_in[4];
  const float* Wk    = (const float*)d_in[5];
  const float* bk    = (const float*)d_in[6];
  const float* Wv    = (const float*)d_in[7];
  const float* bv    = (const float*)d_in[8];
  const float* Wo    = (const float*)d_in[9];
  const float* bo    = (const float*)d_in[10];
  const float* ln_g  = (const float*)d_in[11];
  const float* ln_b  = (const float*)d_in[12];
  float* out = (float*)d_out;

  const size_t HSZ = (size_t)NB*NHEADS*SEQ*DH;   // 2,097,152
  short* Qh  = (short*)d_ws;
  short* Kh  = Qh + HSZ;
  short* Vt  = Kh + HSZ;
  short* ctx = Vt + HSZ;
  short* Wqb = ctx + (size_t)MTOT*DM;
  short* Wkb = Wqb + DM*DM;
  short* Wvb = Wkb + DM*DM;
  short* Wob = Wvb + DM*DM;   // total ws: ~17 MB

  prep<<<dim3(128), 256, 0, stream>>>(Wq, Wk, Wv, Wo, Wqb, Wkb, Wvb, Wob);
  qkv_proj<<<dim3(MTOT/32, 2, 3), 128, 0, stream>>>(
      query, key, value, Wqb, Wkb, Wvb, bq, bk, bv, Qh, Kh, Vt);
  attn<<<dim3(NB*NHEADS, SEQ/32), 256, 0, stream>>>(Qh, Kh, Vt, ctx);
  out_ln<<<dim3(MTOT/16), 256, 0, stream>>>(ctx, Wob, bo, query, ln_g, ln_b, out);
}